// Round 3
// baseline (1093.885 us; speedup 1.0000x reference)
//
#include <hip/hip_runtime.h>
#include <stdint.h>

#define DF 32
#define BN 256               // nodes per bucket (dst >> 8)
#define MAXB 512             // max buckets on fast path (nN <= 131072)
#define CHUNK 4096           // edges per partition WG
typedef unsigned long long u64;

// ======================= bucket partition prepass =======================

// per-bucket edge counts (bcnt must be zeroed)
__global__ void k_bcount(const int* __restrict__ dst, int* __restrict__ bcnt,
                         int nE, int nbuck) {
    __shared__ int h[MAXB];
    for (int i = threadIdx.x; i < MAXB; i += blockDim.x) h[i] = 0;
    __syncthreads();
    for (int i = blockIdx.x * blockDim.x + threadIdx.x; i < nE;
         i += gridDim.x * blockDim.x)
        atomicAdd(&h[dst[i] >> 8], 1);
    __syncthreads();
    for (int i = threadIdx.x; i < nbuck; i += blockDim.x)
        if (h[i]) atomicAdd(&bcnt[i], h[i]);
}

// exclusive scan of bucket counts (one 512-thread WG)
__global__ void k_bscan(const int* __restrict__ bcnt, int* __restrict__ bptr,
                        int* __restrict__ bcur, int nbuck) {
    __shared__ int a[MAXB], b[MAXB];
    int t = threadIdx.x;
    int v = (t < nbuck) ? bcnt[t] : 0;
    a[t] = v;
    __syncthreads();
    int* pin = a; int* pout = b;
    for (int off = 1; off < MAXB; off <<= 1) {
        pout[t] = pin[t] + ((t >= off) ? pin[t - off] : 0);
        __syncthreads();
        int* tmp = pin; pin = pout; pout = tmp;
    }
    int inc = pin[t];            // inclusive scan
    if (t < nbuck) { bptr[t] = inc - v; bcur[t] = inc - v; }
    if (t == nbuck - 1) bptr[nbuck] = inc;
}

// LDS-binned scatter: records land in bucket-contiguous global runs, flushed
// coalesced. record = w(f32)<<32 | src<<8 | localDst (needs nN < 2^24).
__global__ __launch_bounds__(512)
void k_bpart(const int* __restrict__ src, const int* __restrict__ dst,
             const float* __restrict__ w, int* __restrict__ bcur,
             u64* __restrict__ rec_g, int nE, int nbuck) {
    __shared__ u64 rec[CHUNK];
    __shared__ unsigned short rb[CHUNK];
    __shared__ int hist[MAXB], s1[MAXB], s2[MAXB], goff[MAXB], cur[MAXB];
    int t = threadIdx.x;
    int base = blockIdx.x * CHUNK;
    int cnt = min(CHUNK, nE - base);

    hist[t] = 0;
    __syncthreads();

    int myb[8]; u64 myrec[8];
#pragma unroll
    for (int j = 0; j < 8; j++) {
        int i = t + j * 512;                       // coalesced
        if (i < cnt) {
            int d = dst[base + i];
            myb[j] = d >> 8;
            myrec[j] = ((u64)__float_as_uint(w[base + i]) << 32)
                     | ((u64)(unsigned)src[base + i] << 8)
                     | (u64)(d & (BN - 1));
            atomicAdd(&hist[myb[j]], 1);
        } else myb[j] = -1;
    }
    __syncthreads();

    int v = hist[t];
    s1[t] = v;
    __syncthreads();
    int* pin = s1; int* pout = s2;
    for (int off = 1; off < MAXB; off <<= 1) {
        pout[t] = pin[t] + ((t >= off) ? pin[t - off] : 0);
        __syncthreads();
        int* tmp = pin; pin = pout; pout = tmp;
    }
    int excl = pin[t] - v;
    cur[t] = excl;
    int g = 0;
    if (t < nbuck && v > 0) g = atomicAdd(&bcur[t], v);   // reserve global run
    goff[t] = g - excl;
    __syncthreads();

#pragma unroll
    for (int j = 0; j < 8; j++) {
        if (myb[j] >= 0) {
            int p = atomicAdd(&cur[myb[j]], 1);
            rec[p] = myrec[j];
            rb[p] = (unsigned short)myb[j];
        }
    }
    __syncthreads();

    for (int r = t; r < cnt; r += 512) {          // bin-major -> coalesced
        int bb = rb[r];
        rec_g[goff[bb] + r] = rec[r];
    }
}

// ======================= pull SpMM with LDS accumulators =======================
// one WG per bucket; halfwave = one edge; lane f owns feature f.
// MODE: 0 first (out = emb + acc), 1 mid (out += acc), 2 last (out = (out+acc)*0.25)
template <int MODE>
__global__ __launch_bounds__(512)
void k_pull2(const int* __restrict__ bptr, const u64* __restrict__ rec_g,
             const float* __restrict__ h, float* __restrict__ hn,
             const float* __restrict__ emb, float* __restrict__ out, int nN) {
    __shared__ float acc[BN * DF];                // 32 KB
    int t = threadIdx.x;
    for (int i = t; i < BN * DF; i += 512) acc[i] = 0.f;
    __syncthreads();
    int b = blockIdx.x;
    int s0 = bptr[b], s1 = bptr[b + 1];
    int hw = t >> 5, f = t & 31;

    int i = s0 + hw;
    for (; i + 48 < s1; i += 64) {                // 4 gathers in flight
        u64 p0 = rec_g[i], p1 = rec_g[i + 16], p2 = rec_g[i + 32], p3 = rec_g[i + 48];
        float v0 = h[(size_t)((p0 >> 8) & 0xffffff) * DF + f];
        float v1 = h[(size_t)((p1 >> 8) & 0xffffff) * DF + f];
        float v2 = h[(size_t)((p2 >> 8) & 0xffffff) * DF + f];
        float v3 = h[(size_t)((p3 >> 8) & 0xffffff) * DF + f];
        atomicAdd(&acc[(int)(p0 & 255) * DF + f], __uint_as_float((unsigned)(p0 >> 32)) * v0);
        atomicAdd(&acc[(int)(p1 & 255) * DF + f], __uint_as_float((unsigned)(p1 >> 32)) * v1);
        atomicAdd(&acc[(int)(p2 & 255) * DF + f], __uint_as_float((unsigned)(p2 >> 32)) * v2);
        atomicAdd(&acc[(int)(p3 & 255) * DF + f], __uint_as_float((unsigned)(p3 >> 32)) * v3);
    }
    for (; i < s1; i += 16) {
        u64 p = rec_g[i];
        float v = h[(size_t)((p >> 8) & 0xffffff) * DF + f];
        atomicAdd(&acc[(int)(p & 255) * DF + f], __uint_as_float((unsigned)(p >> 32)) * v);
    }
    __syncthreads();

    int nodeBase = b * BN;
    for (int k = t; k < BN * DF; k += 512) {
        int node = nodeBase + (k >> 5);
        if (node < nN) {
            size_t o = (size_t)node * DF + (k & 31);
            float a = acc[k];
            if (MODE == 0)      { hn[o] = a; out[o] = emb[o] + a; }
            else if (MODE == 1) { hn[o] = a; out[o] += a; }
            else                { out[o] = (out[o] + a) * 0.25f; }
        }
    }
}

// ======================= fallback (R1 atomic path) =======================

__global__ void spmm_scatter(const int* __restrict__ src, const int* __restrict__ dst,
                             const float* __restrict__ w, const float* __restrict__ h,
                             float* __restrict__ hn, int nE) {
    int i = blockIdx.x * blockDim.x + threadIdx.x;
    int total = nE * 8;
    if (i >= total) return;
    int e = i >> 3, g = i & 7;
    int s = src[e], t = dst[e];
    float wt = w[e];
    float4 v = reinterpret_cast<const float4*>(h)[(size_t)s * 8 + g];
    float* p = hn + (size_t)t * DF + g * 4;
    atomicAdd(p + 0, v.x * wt); atomicAdd(p + 1, v.y * wt);
    atomicAdd(p + 2, v.z * wt); atomicAdd(p + 3, v.w * wt);
}
__global__ void accum_first(const float* __restrict__ emb, const float* __restrict__ hn,
                            float* __restrict__ out, int n4) {
    int i = blockIdx.x * blockDim.x + threadIdx.x;
    if (i >= n4) return;
    float4 a = reinterpret_cast<const float4*>(emb)[i];
    float4 b = reinterpret_cast<const float4*>(hn)[i];
    reinterpret_cast<float4*>(out)[i] = make_float4(a.x+b.x, a.y+b.y, a.z+b.z, a.w+b.w);
}
__global__ void accum_mid(const float* __restrict__ hn, float* __restrict__ out, int n4) {
    int i = blockIdx.x * blockDim.x + threadIdx.x;
    if (i >= n4) return;
    float4 a = reinterpret_cast<float4*>(out)[i];
    float4 b = reinterpret_cast<const float4*>(hn)[i];
    reinterpret_cast<float4*>(out)[i] = make_float4(a.x+b.x, a.y+b.y, a.z+b.z, a.w+b.w);
}
__global__ void accum_last(const float* __restrict__ hn, float* __restrict__ out, int n4) {
    int i = blockIdx.x * blockDim.x + threadIdx.x;
    if (i >= n4) return;
    float4 a = reinterpret_cast<float4*>(out)[i];
    float4 b = reinterpret_cast<const float4*>(hn)[i];
    reinterpret_cast<float4*>(out)[i] = make_float4((a.x+b.x)*0.25f, (a.y+b.y)*0.25f,
                                                    (a.z+b.z)*0.25f, (a.w+b.w)*0.25f);
}

// ======================= launch =======================

extern "C" void kernel_launch(void* const* d_in, const int* in_sizes, int n_in,
                              void* d_out, int out_size, void* d_ws, size_t ws_size,
                              hipStream_t stream) {
    const float* emb = (const float*)d_in[0];
    const int*   src = (const int*)d_in[1];
    const int*   dst = (const int*)d_in[2];
    const float* w   = (const float*)d_in[3];
    float* out = (float*)d_out;

    const int nN = in_sizes[0] / DF;
    const int nE = in_sizes[1];
    const int nbuck = (nN + BN - 1) / BN;
    const size_t hbytes = (size_t)nN * DF * sizeof(float);

    char* ws = (char*)d_ws;
    float* A = (float*)ws;
    float* B = (float*)(ws + hbytes);
    u64* rec_g = (u64*)(ws + 2 * hbytes);
    size_t o4 = 2 * hbytes + (size_t)nE * 8;
    o4 = ((o4 + 63) / 64) * 64;
    int* bcnt = (int*)(ws + o4);
    int* bptr = bcnt + MAXB;
    int* bcur = bptr + MAXB + 1;
    const size_t need = o4 + (size_t)(3 * MAXB + 1) * 4;

    const dim3 blk(256);

    if (nbuck <= MAXB && nN < (1 << 24) && ws_size >= need) {
        hipMemsetAsync(bcnt, 0, MAXB * 4, stream);
        k_bcount<<<512, blk, 0, stream>>>(dst, bcnt, nE, nbuck);
        k_bscan<<<1, MAXB, 0, stream>>>(bcnt, bptr, bcur, nbuck);
        k_bpart<<<(nE + CHUNK - 1) / CHUNK, 512, 0, stream>>>(src, dst, w, bcur,
                                                              rec_g, nE, nbuck);
        k_pull2<0><<<nbuck, 512, 0, stream>>>(bptr, rec_g, emb, B, emb, out, nN);
        k_pull2<1><<<nbuck, 512, 0, stream>>>(bptr, rec_g, B,   A, emb, out, nN);
        k_pull2<2><<<nbuck, 512, 0, stream>>>(bptr, rec_g, A,   B, emb, out, nN);
    } else {
        const int n4 = nN * DF / 4;
        const int sgrid = (nE * 8 + 255) / 256;
        const int agrid = (n4 + 255) / 256;
        hipMemsetAsync(B, 0, hbytes, stream);
        spmm_scatter<<<sgrid, blk, 0, stream>>>(src, dst, w, emb, B, nE);
        accum_first<<<agrid, blk, 0, stream>>>(emb, B, out, n4);
        hipMemsetAsync(A, 0, hbytes, stream);
        spmm_scatter<<<sgrid, blk, 0, stream>>>(src, dst, w, B, A, nE);
        accum_mid<<<agrid, blk, 0, stream>>>(A, out, n4);
        hipMemsetAsync(B, 0, hbytes, stream);
        spmm_scatter<<<sgrid, blk, 0, stream>>>(src, dst, w, A, B, nE);
        accum_last<<<agrid, blk, 0, stream>>>(B, out, n4);
    }
}

// Round 4
// 330.867 us; speedup vs baseline: 3.3061x; 3.3061x over previous
//
#include <hip/hip_runtime.h>
#include <stdint.h>

#define DF 32
typedef unsigned long long u64;

// ======================= CSR prepass =======================

__global__ void k_hist(const int* __restrict__ dst, int* __restrict__ cnt, int nE) {
    int i = blockIdx.x * blockDim.x + threadIdx.x;
    if (i < nE) atomicAdd(&cnt[dst[i]], 1);
}

__global__ void k_partial(const int* __restrict__ cnt, int* __restrict__ part, int n) {
    __shared__ int sm[256];
    int t = threadIdx.x;
    int base = blockIdx.x * 1024 + t * 4;
    int s = 0;
#pragma unroll
    for (int j = 0; j < 4; j++) { int idx = base + j; if (idx < n) s += cnt[idx]; }
    sm[t] = s; __syncthreads();
    for (int off = 128; off > 0; off >>= 1) { if (t < off) sm[t] += sm[t + off]; __syncthreads(); }
    if (t == 0) part[blockIdx.x] = sm[0];
}

__global__ void k_scanpart(const int* __restrict__ part, int* __restrict__ partex, int np) {
    __shared__ int sm[128];
    int t = threadIdx.x;
    int v = (t < np) ? part[t] : 0;
    sm[t] = v; __syncthreads();
    for (int off = 1; off < 128; off <<= 1) {
        int u = (t >= off) ? sm[t - off] : 0; __syncthreads();
        sm[t] += u; __syncthreads();
    }
    if (t < np) partex[t] = sm[t] - v;
}

// NOTE: cnt and cursor may alias (each element read before written by its owner thread)
__global__ void k_scan(const int* __restrict__ cnt, const int* __restrict__ partex,
                       int* __restrict__ rowptr, int* __restrict__ cursor, int n) {
    __shared__ int sm[256];
    int t = threadIdx.x;
    int base = blockIdx.x * 1024 + t * 4;
    int c[4]; int s = 0;
#pragma unroll
    for (int j = 0; j < 4; j++) { int idx = base + j; c[j] = (idx < n) ? cnt[idx] : 0; s += c[j]; }
    sm[t] = s; __syncthreads();
    for (int off = 1; off < 256; off <<= 1) {
        int u = (t >= off) ? sm[t - off] : 0; __syncthreads();
        sm[t] += u; __syncthreads();
    }
    int run = partex[blockIdx.x] + sm[t] - s;
#pragma unroll
    for (int j = 0; j < 4; j++) {
        int idx = base + j;
        if (idx < n) { rowptr[idx] = run; cursor[idx] = run; run += c[j]; }
    }
    if (base <= n - 1 && n - 1 < base + 4) rowptr[n] = run;
}

__global__ void k_scatter(const int* __restrict__ src, const int* __restrict__ dst,
                          const float* __restrict__ w, int* __restrict__ cursor,
                          u64* __restrict__ packed, int nE) {
    int i = blockIdx.x * blockDim.x + threadIdx.x;
    if (i >= nE) return;
    int d = dst[i];
    int pos = atomicAdd(&cursor[d], 1);
    packed[pos] = ((u64)__float_as_uint(w[i]) << 32) | (unsigned)src[i];
}

// ======================= pull SpMM (unroll-4 MLP) =======================
// half-wave per node: lane f (0..31) owns feature f. MODE: 0 first layer
// (out = emb + acc), 1 middle (out += acc), 2 last (out = (out+acc)*0.25, no hn)
template <int MODE>
__global__ void k_pull(const int* __restrict__ rowptr, const u64* __restrict__ packed,
                       const float* __restrict__ h, float* __restrict__ hn,
                       const float* __restrict__ emb, float* __restrict__ out, int n) {
    int gid = blockIdx.x * blockDim.x + threadIdx.x;
    int node = gid >> 5;
    int f = gid & 31;
    if (node >= n) return;
    int s0 = rowptr[node], s1 = rowptr[node + 1];
    float acc0 = 0.f, acc1 = 0.f, acc2 = 0.f, acc3 = 0.f;
    int i = s0;
    for (; i + 4 <= s1; i += 4) {                 // 4 gathers in flight
        u64 p0 = packed[i], p1 = packed[i + 1], p2 = packed[i + 2], p3 = packed[i + 3];
        float v0 = h[(size_t)(unsigned)(p0 & 0xffffffffu) * DF + f];
        float v1 = h[(size_t)(unsigned)(p1 & 0xffffffffu) * DF + f];
        float v2 = h[(size_t)(unsigned)(p2 & 0xffffffffu) * DF + f];
        float v3 = h[(size_t)(unsigned)(p3 & 0xffffffffu) * DF + f];
        acc0 += __uint_as_float((unsigned)(p0 >> 32)) * v0;
        acc1 += __uint_as_float((unsigned)(p1 >> 32)) * v1;
        acc2 += __uint_as_float((unsigned)(p2 >> 32)) * v2;
        acc3 += __uint_as_float((unsigned)(p3 >> 32)) * v3;
    }
    for (; i < s1; i++) {
        u64 p = packed[i];
        acc0 += __uint_as_float((unsigned)(p >> 32))
              * h[(size_t)(unsigned)(p & 0xffffffffu) * DF + f];
    }
    float acc = (acc0 + acc1) + (acc2 + acc3);
    size_t o = (size_t)node * DF + f;
    if (MODE == 0)      { hn[o] = acc; out[o] = emb[o] + acc; }
    else if (MODE == 1) { hn[o] = acc; out[o] += acc; }
    else                { out[o] = (out[o] + acc) * 0.25f; }
}

// ======================= fallback (R1 atomic path) =======================

__global__ void spmm_scatter(const int* __restrict__ src, const int* __restrict__ dst,
                             const float* __restrict__ w, const float* __restrict__ h,
                             float* __restrict__ hn, int nE) {
    int i = blockIdx.x * blockDim.x + threadIdx.x;
    int total = nE * 8;
    if (i >= total) return;
    int e = i >> 3, g = i & 7;
    int s = src[e], t = dst[e];
    float wt = w[e];
    float4 v = reinterpret_cast<const float4*>(h)[(size_t)s * 8 + g];
    float* p = hn + (size_t)t * DF + g * 4;
    atomicAdd(p + 0, v.x * wt); atomicAdd(p + 1, v.y * wt);
    atomicAdd(p + 2, v.z * wt); atomicAdd(p + 3, v.w * wt);
}
__global__ void accum_first(const float* __restrict__ emb, const float* __restrict__ hn,
                            float* __restrict__ out, int n4) {
    int i = blockIdx.x * blockDim.x + threadIdx.x;
    if (i >= n4) return;
    float4 a = reinterpret_cast<const float4*>(emb)[i];
    float4 b = reinterpret_cast<const float4*>(hn)[i];
    reinterpret_cast<float4*>(out)[i] = make_float4(a.x+b.x, a.y+b.y, a.z+b.z, a.w+b.w);
}
__global__ void accum_mid(const float* __restrict__ hn, float* __restrict__ out, int n4) {
    int i = blockIdx.x * blockDim.x + threadIdx.x;
    if (i >= n4) return;
    float4 a = reinterpret_cast<float4*>(out)[i];
    float4 b = reinterpret_cast<const float4*>(hn)[i];
    reinterpret_cast<float4*>(out)[i] = make_float4(a.x+b.x, a.y+b.y, a.z+b.z, a.w+b.w);
}
__global__ void accum_last(const float* __restrict__ hn, float* __restrict__ out, int n4) {
    int i = blockIdx.x * blockDim.x + threadIdx.x;
    if (i >= n4) return;
    float4 a = reinterpret_cast<float4*>(out)[i];
    float4 b = reinterpret_cast<const float4*>(hn)[i];
    reinterpret_cast<float4*>(out)[i] = make_float4((a.x+b.x)*0.25f, (a.y+b.y)*0.25f,
                                                    (a.z+b.z)*0.25f, (a.w+b.w)*0.25f);
}

// ======================= launch =======================

extern "C" void kernel_launch(void* const* d_in, const int* in_sizes, int n_in,
                              void* d_out, int out_size, void* d_ws, size_t ws_size,
                              hipStream_t stream) {
    const float* emb = (const float*)d_in[0];
    const int*   src = (const int*)d_in[1];
    const int*   dst = (const int*)d_in[2];
    const float* w   = (const float*)d_in[3];
    float* out = (float*)d_out;

    const int nN = in_sizes[0] / DF;
    const int nE = in_sizes[1];
    const size_t hbytes = (size_t)nN * DF * sizeof(float);

    char* ws = (char*)d_ws;
    float* A = (float*)ws;
    float* B = (float*)(ws + hbytes);
    u64* packed = (u64*)(ws + 2 * hbytes);
    size_t roff = 2 * hbytes + (size_t)nE * 8;
    roff = ((roff + 63) / 64) * 64;
    int* rowptr = (int*)(ws + roff);
    size_t coff = roff + (((size_t)(nN + 1) * 4 + 63) / 64) * 64;
    int* cursor = (int*)(ws + coff);        // doubles as counts
    size_t poff = coff + (((size_t)nN * 4 + 63) / 64) * 64;
    int* part   = (int*)(ws + poff);
    int* partex = part + 128;

    const int NB = (nN + 1023) / 1024;
    const size_t need = poff + 256 * sizeof(int) + 1024;

    const dim3 blk(256);

    if (ws_size >= need && NB <= 128) {
        hipMemsetAsync(cursor, 0, (size_t)nN * 4, stream);
        k_hist<<<(nE + 255) / 256, blk, 0, stream>>>(dst, cursor, nE);
        k_partial<<<NB, blk, 0, stream>>>(cursor, part, nN);
        k_scanpart<<<1, 128, 0, stream>>>(part, partex, NB);
        k_scan<<<NB, blk, 0, stream>>>(cursor, partex, rowptr, cursor, nN);
        k_scatter<<<(nE + 255) / 256, blk, 0, stream>>>(src, dst, w, cursor, packed, nE);

        const int pgrid = (nN * 32 + 255) / 256;
        k_pull<0><<<pgrid, blk, 0, stream>>>(rowptr, packed, emb, B, emb, out, nN);
        k_pull<1><<<pgrid, blk, 0, stream>>>(rowptr, packed, B,   A, emb, out, nN);
        k_pull<2><<<pgrid, blk, 0, stream>>>(rowptr, packed, A,   B, emb, out, nN);
    } else {
        const int n4 = nN * DF / 4;
        const int sgrid = (nE * 8 + 255) / 256;
        const int agrid = (n4 + 255) / 256;
        hipMemsetAsync(B, 0, hbytes, stream);
        spmm_scatter<<<sgrid, blk, 0, stream>>>(src, dst, w, emb, B, nE);
        accum_first<<<agrid, blk, 0, stream>>>(emb, B, out, n4);
        hipMemsetAsync(A, 0, hbytes, stream);
        spmm_scatter<<<sgrid, blk, 0, stream>>>(src, dst, w, B, A, nE);
        accum_mid<<<agrid, blk, 0, stream>>>(A, out, n4);
        hipMemsetAsync(B, 0, hbytes, stream);
        spmm_scatter<<<sgrid, blk, 0, stream>>>(src, dst, w, A, B, nE);
        accum_last<<<agrid, blk, 0, stream>>>(B, out, n4);
    }
}

// Round 5
// 189.092 us; speedup vs baseline: 5.7849x; 1.7498x over previous
//
#include <hip/hip_runtime.h>
#include <stdint.h>

#define DF 32
#define BN 256               // nodes per bucket (dst >> 8)
#define MAXB 512             // max buckets on fast path (nN <= 131072)
#define CHUNK 4096           // edges per partition WG
typedef unsigned long long u64;

// ======================= bucket partition prepass =======================

// per-bucket edge counts (bcnt must be zeroed)
__global__ void k_bcount(const int* __restrict__ dst, int* __restrict__ bcnt,
                         int nE, int nbuck) {
    __shared__ int h[MAXB];
    for (int i = threadIdx.x; i < MAXB; i += blockDim.x) h[i] = 0;
    __syncthreads();
    for (int i = blockIdx.x * blockDim.x + threadIdx.x; i < nE;
         i += gridDim.x * blockDim.x)
        atomicAdd(&h[dst[i] >> 8], 1);
    __syncthreads();
    for (int i = threadIdx.x; i < nbuck; i += blockDim.x)
        if (h[i]) atomicAdd(&bcnt[i], h[i]);
}

// exclusive scan of bucket counts (one MAXB-thread WG)
__global__ void k_bscan(const int* __restrict__ bcnt, int* __restrict__ bptr,
                        int* __restrict__ bcur, int nbuck) {
    __shared__ int a[MAXB], b[MAXB];
    int t = threadIdx.x;
    int v = (t < nbuck) ? bcnt[t] : 0;
    a[t] = v;
    __syncthreads();
    int* pin = a; int* pout = b;
    for (int off = 1; off < MAXB; off <<= 1) {
        pout[t] = pin[t] + ((t >= off) ? pin[t - off] : 0);
        __syncthreads();
        int* tmp = pin; pin = pout; pout = tmp;
    }
    int inc = pin[t];            // inclusive scan
    if (t < nbuck) { bptr[t] = inc - v; bcur[t] = inc - v; }
    if (t == nbuck - 1) bptr[nbuck] = inc;
}

// LDS-binned scatter: records land in bucket-contiguous global runs, flushed
// coalesced. record = w(f32)<<32 | src<<8 | localDst (needs nN < 2^24).
__global__ __launch_bounds__(512)
void k_bpart(const int* __restrict__ src, const int* __restrict__ dst,
             const float* __restrict__ w, int* __restrict__ bcur,
             u64* __restrict__ rec_g, int nE, int nbuck) {
    __shared__ u64 rec[CHUNK];
    __shared__ unsigned short rb[CHUNK];
    __shared__ int hist[MAXB], sa[MAXB], sb[MAXB], goff[MAXB], cur[MAXB];
    int t = threadIdx.x;
    int base = blockIdx.x * CHUNK;
    int cnt = min(CHUNK, nE - base);

    hist[t] = 0;
    __syncthreads();

    int myb[8]; u64 myrec[8];
#pragma unroll
    for (int j = 0; j < 8; j++) {
        int i = t + j * 512;                       // coalesced
        if (i < cnt) {
            int d = dst[base + i];
            myb[j] = d >> 8;
            myrec[j] = ((u64)__float_as_uint(w[base + i]) << 32)
                     | ((u64)(unsigned)src[base + i] << 8)
                     | (u64)(d & (BN - 1));
            atomicAdd(&hist[myb[j]], 1);
        } else myb[j] = -1;
    }
    __syncthreads();

    int v = hist[t];
    sa[t] = v;
    __syncthreads();
    int* pin = sa; int* pout = sb;
    for (int off = 1; off < MAXB; off <<= 1) {
        pout[t] = pin[t] + ((t >= off) ? pin[t - off] : 0);
        __syncthreads();
        int* tmp = pin; pin = pout; pout = tmp;
    }
    int excl = pin[t] - v;
    cur[t] = excl;
    int g = 0;
    if (t < nbuck && v > 0) g = atomicAdd(&bcur[t], v);   // reserve global run
    goff[t] = g - excl;
    __syncthreads();

#pragma unroll
    for (int j = 0; j < 8; j++) {
        if (myb[j] >= 0) {
            int p = atomicAdd(&cur[myb[j]], 1);
            rec[p] = myrec[j];
            rb[p] = (unsigned short)myb[j];
        }
    }
    __syncthreads();

    for (int r = t; r < cnt; r += 512) {          // bin-major -> coalesced
        int bb = rb[r];
        rec_g[goff[bb] + r] = rec[r];
    }
}

// one WG per bucket: build exact CSR (rowptr + placed records) from the
// bucket-sorted rec_g. Writes stay inside the bucket's output window -> L2-merged.
__global__ __launch_bounds__(512)
void k_csr(const int* __restrict__ bptr, const u64* __restrict__ rec_g,
           int* __restrict__ rowptr, u64* __restrict__ packed, int nN, int nbuck) {
    __shared__ int cnt[BN], excl[BN];
    int b = blockIdx.x;
    int t = threadIdx.x;
    int s0 = bptr[b], s1 = bptr[b + 1];
    if (t < BN) cnt[t] = 0;
    __syncthreads();
    for (int i = s0 + t; i < s1; i += 512)
        atomicAdd(&cnt[(int)(rec_g[i] & (BN - 1))], 1);
    __syncthreads();
    if (t < BN) excl[t] = cnt[t];
    __syncthreads();
    for (int off = 1; off < BN; off <<= 1) {       // Hillis-Steele inclusive
        int u = 0;
        if (t < BN && t >= off) u = excl[t - off];
        __syncthreads();
        if (t < BN) excl[t] += u;
        __syncthreads();
    }
    int nodeBase = b * BN;
    if (t < BN) {
        int e = excl[t] - cnt[t];                  // exclusive
        if (nodeBase + t < nN) rowptr[nodeBase + t] = s0 + e;
        cnt[t] = e;                                // reuse as cursor
    }
    if (b == nbuck - 1 && t == 0) rowptr[nN] = s1;
    __syncthreads();
    for (int i = s0 + t; i < s1; i += 512) {
        u64 r = rec_g[i];
        int ld = (int)(r & (BN - 1));
        int pos = s0 + atomicAdd(&cnt[ld], 1);
        packed[pos] = (r & 0xffffffff00000000ull) | ((r >> 8) & 0xffffffull);
    }
}

// ======================= pull SpMM (unroll-4 MLP) =======================
// half-wave per node: lane f (0..31) owns feature f. MODE: 0 first layer
// (out = emb + acc), 1 middle (out += acc), 2 last (out = (out+acc)*0.25, no hn)
template <int MODE>
__global__ void k_pull(const int* __restrict__ rowptr, const u64* __restrict__ packed,
                       const float* __restrict__ h, float* __restrict__ hn,
                       const float* __restrict__ emb, float* __restrict__ out, int n) {
    int gid = blockIdx.x * blockDim.x + threadIdx.x;
    int node = gid >> 5;
    int f = gid & 31;
    if (node >= n) return;
    int s0 = rowptr[node], s1 = rowptr[node + 1];
    float acc0 = 0.f, acc1 = 0.f, acc2 = 0.f, acc3 = 0.f;
    int i = s0;
    for (; i + 4 <= s1; i += 4) {                 // 4 gathers in flight
        u64 p0 = packed[i], p1 = packed[i + 1], p2 = packed[i + 2], p3 = packed[i + 3];
        float v0 = h[(size_t)(unsigned)(p0 & 0xffffffffu) * DF + f];
        float v1 = h[(size_t)(unsigned)(p1 & 0xffffffffu) * DF + f];
        float v2 = h[(size_t)(unsigned)(p2 & 0xffffffffu) * DF + f];
        float v3 = h[(size_t)(unsigned)(p3 & 0xffffffffu) * DF + f];
        acc0 += __uint_as_float((unsigned)(p0 >> 32)) * v0;
        acc1 += __uint_as_float((unsigned)(p1 >> 32)) * v1;
        acc2 += __uint_as_float((unsigned)(p2 >> 32)) * v2;
        acc3 += __uint_as_float((unsigned)(p3 >> 32)) * v3;
    }
    for (; i < s1; i++) {
        u64 p = packed[i];
        acc0 += __uint_as_float((unsigned)(p >> 32))
              * h[(size_t)(unsigned)(p & 0xffffffffu) * DF + f];
    }
    float acc = (acc0 + acc1) + (acc2 + acc3);
    size_t o = (size_t)node * DF + f;
    if (MODE == 0)      { hn[o] = acc; out[o] = emb[o] + acc; }
    else if (MODE == 1) { hn[o] = acc; out[o] += acc; }
    else                { out[o] = (out[o] + acc) * 0.25f; }
}

// ======================= fallback (R1 atomic path) =======================

__global__ void spmm_scatter(const int* __restrict__ src, const int* __restrict__ dst,
                             const float* __restrict__ w, const float* __restrict__ h,
                             float* __restrict__ hn, int nE) {
    int i = blockIdx.x * blockDim.x + threadIdx.x;
    int total = nE * 8;
    if (i >= total) return;
    int e = i >> 3, g = i & 7;
    int s = src[e], t = dst[e];
    float wt = w[e];
    float4 v = reinterpret_cast<const float4*>(h)[(size_t)s * 8 + g];
    float* p = hn + (size_t)t * DF + g * 4;
    atomicAdd(p + 0, v.x * wt); atomicAdd(p + 1, v.y * wt);
    atomicAdd(p + 2, v.z * wt); atomicAdd(p + 3, v.w * wt);
}
__global__ void accum_first(const float* __restrict__ emb, const float* __restrict__ hn,
                            float* __restrict__ out, int n4) {
    int i = blockIdx.x * blockDim.x + threadIdx.x;
    if (i >= n4) return;
    float4 a = reinterpret_cast<const float4*>(emb)[i];
    float4 b = reinterpret_cast<const float4*>(hn)[i];
    reinterpret_cast<float4*>(out)[i] = make_float4(a.x+b.x, a.y+b.y, a.z+b.z, a.w+b.w);
}
__global__ void accum_mid(const float* __restrict__ hn, float* __restrict__ out, int n4) {
    int i = blockIdx.x * blockDim.x + threadIdx.x;
    if (i >= n4) return;
    float4 a = reinterpret_cast<float4*>(out)[i];
    float4 b = reinterpret_cast<const float4*>(hn)[i];
    reinterpret_cast<float4*>(out)[i] = make_float4(a.x+b.x, a.y+b.y, a.z+b.z, a.w+b.w);
}
__global__ void accum_last(const float* __restrict__ hn, float* __restrict__ out, int n4) {
    int i = blockIdx.x * blockDim.x + threadIdx.x;
    if (i >= n4) return;
    float4 a = reinterpret_cast<float4*>(out)[i];
    float4 b = reinterpret_cast<const float4*>(hn)[i];
    reinterpret_cast<float4*>(out)[i] = make_float4((a.x+b.x)*0.25f, (a.y+b.y)*0.25f,
                                                    (a.z+b.z)*0.25f, (a.w+b.w)*0.25f);
}

// ======================= launch =======================

extern "C" void kernel_launch(void* const* d_in, const int* in_sizes, int n_in,
                              void* d_out, int out_size, void* d_ws, size_t ws_size,
                              hipStream_t stream) {
    const float* emb = (const float*)d_in[0];
    const int*   src = (const int*)d_in[1];
    const int*   dst = (const int*)d_in[2];
    const float* w   = (const float*)d_in[3];
    float* out = (float*)d_out;

    const int nN = in_sizes[0] / DF;
    const int nE = in_sizes[1];
    const int nbuck = (nN + BN - 1) / BN;
    const size_t hbytes = (size_t)nN * DF * sizeof(float);

    char* ws = (char*)d_ws;
    float* A = (float*)ws;
    float* B = (float*)(ws + hbytes);
    u64* rec_g = (u64*)ws;                        // overlaps A/B; dead before pulls
    u64* packed = (u64*)(ws + 2 * hbytes);
    size_t roff = 2 * hbytes + (size_t)nE * 8;
    roff = ((roff + 63) / 64) * 64;
    int* rowptr = (int*)(ws + roff);
    size_t boff = roff + (((size_t)(nN + 1) * 4 + 63) / 64) * 64;
    int* bcnt = (int*)(ws + boff);
    int* bptr = bcnt + MAXB;
    int* bcur = bptr + MAXB + 1;
    const size_t need = boff + (size_t)(3 * MAXB + 1) * 4;

    const dim3 blk(256);

    if (nbuck <= MAXB && nN < (1 << 24) && (size_t)nE * 8 <= 2 * hbytes &&
        ws_size >= need) {
        hipMemsetAsync(bcnt, 0, MAXB * 4, stream);
        k_bcount<<<512, blk, 0, stream>>>(dst, bcnt, nE, nbuck);
        k_bscan<<<1, MAXB, 0, stream>>>(bcnt, bptr, bcur, nbuck);
        k_bpart<<<(nE + CHUNK - 1) / CHUNK, 512, 0, stream>>>(src, dst, w, bcur,
                                                              rec_g, nE, nbuck);
        k_csr<<<nbuck, 512, 0, stream>>>(bptr, rec_g, rowptr, packed, nN, nbuck);

        const int pgrid = (nN * 32 + 255) / 256;
        k_pull<0><<<pgrid, blk, 0, stream>>>(rowptr, packed, emb, B, emb, out, nN);
        k_pull<1><<<pgrid, blk, 0, stream>>>(rowptr, packed, B,   A, emb, out, nN);
        k_pull<2><<<pgrid, blk, 0, stream>>>(rowptr, packed, A,   B, emb, out, nN);
    } else {
        const int n4 = nN * DF / 4;
        const int sgrid = (nE * 8 + 255) / 256;
        const int agrid = (n4 + 255) / 256;
        hipMemsetAsync(B, 0, hbytes, stream);
        spmm_scatter<<<sgrid, blk, 0, stream>>>(src, dst, w, emb, B, nE);
        accum_first<<<agrid, blk, 0, stream>>>(emb, B, out, n4);
        hipMemsetAsync(A, 0, hbytes, stream);
        spmm_scatter<<<sgrid, blk, 0, stream>>>(src, dst, w, B, A, nE);
        accum_mid<<<agrid, blk, 0, stream>>>(A, out, n4);
        hipMemsetAsync(B, 0, hbytes, stream);
        spmm_scatter<<<sgrid, blk, 0, stream>>>(src, dst, w, A, B, nE);
        accum_last<<<agrid, blk, 0, stream>>>(B, out, n4);
    }
}

// Round 6
// 188.802 us; speedup vs baseline: 5.7938x; 1.0015x over previous
//
#include <hip/hip_runtime.h>
#include <stdint.h>

#define DF 32
#define BN 256               // nodes per bucket (dst >> 8)
#define MAXB 512             // max buckets on fast path (nN <= 131072)
#define CHUNK 4096           // edges per partition WG
typedef unsigned long long u64;
typedef unsigned short u16;

static __device__ __forceinline__ u16 f2bf(float x) {     // RTN-even
    unsigned u = __float_as_uint(x);
    return (u16)((u + 0x7fff + ((u >> 16) & 1)) >> 16);
}
static __device__ __forceinline__ float bf2f(u16 b) {
    return __uint_as_float((unsigned)b << 16);
}

// ======================= bucket partition prepass =======================

__global__ void k_bcount(const int* __restrict__ dst, int* __restrict__ bcnt,
                         int nE, int nbuck) {
    __shared__ int h[MAXB];
    for (int i = threadIdx.x; i < MAXB; i += blockDim.x) h[i] = 0;
    __syncthreads();
    for (int i = blockIdx.x * blockDim.x + threadIdx.x; i < nE;
         i += gridDim.x * blockDim.x)
        atomicAdd(&h[dst[i] >> 8], 1);
    __syncthreads();
    for (int i = threadIdx.x; i < nbuck; i += blockDim.x)
        if (h[i]) atomicAdd(&bcnt[i], h[i]);
}

__global__ void k_bscan(const int* __restrict__ bcnt, int* __restrict__ bptr,
                        int* __restrict__ bcur, int nbuck) {
    __shared__ int a[MAXB], b[MAXB];
    int t = threadIdx.x;
    int v = (t < nbuck) ? bcnt[t] : 0;
    a[t] = v;
    __syncthreads();
    int* pin = a; int* pout = b;
    for (int off = 1; off < MAXB; off <<= 1) {
        pout[t] = pin[t] + ((t >= off) ? pin[t - off] : 0);
        __syncthreads();
        int* tmp = pin; pin = pout; pout = tmp;
    }
    int inc = pin[t];
    if (t < nbuck) { bptr[t] = inc - v; bcur[t] = inc - v; }
    if (t == nbuck - 1) bptr[nbuck] = inc;
}

// record = w(f32)<<32 | src<<8 | localDst  (needs nN < 2^24)
__global__ __launch_bounds__(512)
void k_bpart(const int* __restrict__ src, const int* __restrict__ dst,
             const float* __restrict__ w, int* __restrict__ bcur,
             u64* __restrict__ rec_g, int nE, int nbuck) {
    __shared__ u64 rec[CHUNK];
    __shared__ unsigned short rb[CHUNK];
    __shared__ int hist[MAXB], sa[MAXB], sb[MAXB], goff[MAXB], cur[MAXB];
    int t = threadIdx.x;
    int base = blockIdx.x * CHUNK;
    int cnt = min(CHUNK, nE - base);

    hist[t] = 0;
    __syncthreads();

    int myb[8]; u64 myrec[8];
#pragma unroll
    for (int j = 0; j < 8; j++) {
        int i = t + j * 512;
        if (i < cnt) {
            int d = dst[base + i];
            myb[j] = d >> 8;
            myrec[j] = ((u64)__float_as_uint(w[base + i]) << 32)
                     | ((u64)(unsigned)src[base + i] << 8)
                     | (u64)(d & (BN - 1));
            atomicAdd(&hist[myb[j]], 1);
        } else myb[j] = -1;
    }
    __syncthreads();

    int v = hist[t];
    sa[t] = v;
    __syncthreads();
    int* pin = sa; int* pout = sb;
    for (int off = 1; off < MAXB; off <<= 1) {
        pout[t] = pin[t] + ((t >= off) ? pin[t - off] : 0);
        __syncthreads();
        int* tmp = pin; pin = pout; pout = tmp;
    }
    int excl = pin[t] - v;
    cur[t] = excl;
    int g = 0;
    if (t < nbuck && v > 0) g = atomicAdd(&bcur[t], v);
    goff[t] = g - excl;
    __syncthreads();

#pragma unroll
    for (int j = 0; j < 8; j++) {
        if (myb[j] >= 0) {
            int p = atomicAdd(&cur[myb[j]], 1);
            rec[p] = myrec[j];
            rb[p] = (unsigned short)myb[j];
        }
    }
    __syncthreads();

    for (int r = t; r < cnt; r += 512) {
        int bb = rb[r];
        rec_g[goff[bb] + r] = rec[r];
    }
}

// one WG per bucket: exact CSR from bucket-sorted rec_g
__global__ __launch_bounds__(512)
void k_csr(const int* __restrict__ bptr, const u64* __restrict__ rec_g,
           int* __restrict__ rowptr, u64* __restrict__ packed, int nN, int nbuck) {
    __shared__ int cnt[BN], excl[BN];
    int b = blockIdx.x;
    int t = threadIdx.x;
    int s0 = bptr[b], s1 = bptr[b + 1];
    if (t < BN) cnt[t] = 0;
    __syncthreads();
    for (int i = s0 + t; i < s1; i += 512)
        atomicAdd(&cnt[(int)(rec_g[i] & (BN - 1))], 1);
    __syncthreads();
    if (t < BN) excl[t] = cnt[t];
    __syncthreads();
    for (int off = 1; off < BN; off <<= 1) {
        int u = 0;
        if (t < BN && t >= off) u = excl[t - off];
        __syncthreads();
        if (t < BN) excl[t] += u;
        __syncthreads();
    }
    int nodeBase = b * BN;
    if (t < BN) {
        int e = excl[t] - cnt[t];
        if (nodeBase + t < nN) rowptr[nodeBase + t] = s0 + e;
        cnt[t] = e;
    }
    if (b == nbuck - 1 && t == 0) rowptr[nN] = s1;
    __syncthreads();
    for (int i = s0 + t; i < s1; i += 512) {
        u64 r = rec_g[i];
        int ld = (int)(r & (BN - 1));
        int pos = s0 + atomicAdd(&cnt[ld], 1);
        packed[pos] = (r & 0xffffffff00000000ull) | ((r >> 8) & 0xffffffull);
    }
}

// f32 -> bf16 cast (4 elems/thread)
__global__ void k_cast(const float* __restrict__ x, u16* __restrict__ y, int n4) {
    int i = blockIdx.x * blockDim.x + threadIdx.x;
    if (i >= n4) return;
    float4 v = reinterpret_cast<const float4*>(x)[i];
    ushort4 o;
    o.x = f2bf(v.x); o.y = f2bf(v.y); o.z = f2bf(v.z); o.w = f2bf(v.w);
    reinterpret_cast<ushort4*>(y)[i] = o;
}

// ======================= pull SpMM (bf16 gathers, unroll-4 MLP) ==============
// half-wave per node: lane f owns feature f. MODE: 0 first layer
// (out = emb + acc, hn=bf16(acc)), 1 mid (out += acc, hn=bf16(acc)),
// 2 last (out = (out+acc)*0.25, no hn)
template <int MODE>
__global__ void k_pull(const int* __restrict__ rowptr, const u64* __restrict__ packed,
                       const u16* __restrict__ h16, u16* __restrict__ hn16,
                       const float* __restrict__ emb, float* __restrict__ out, int n) {
    int gid = blockIdx.x * blockDim.x + threadIdx.x;
    int node = gid >> 5;
    int f = gid & 31;
    if (node >= n) return;
    int s0 = rowptr[node], s1 = rowptr[node + 1];
    float acc0 = 0.f, acc1 = 0.f, acc2 = 0.f, acc3 = 0.f;
    int i = s0;
    for (; i + 4 <= s1; i += 4) {                 // 4 gathers in flight
        u64 p0 = packed[i], p1 = packed[i + 1], p2 = packed[i + 2], p3 = packed[i + 3];
        float v0 = bf2f(h16[(size_t)(unsigned)(p0 & 0xffffffffu) * DF + f]);
        float v1 = bf2f(h16[(size_t)(unsigned)(p1 & 0xffffffffu) * DF + f]);
        float v2 = bf2f(h16[(size_t)(unsigned)(p2 & 0xffffffffu) * DF + f]);
        float v3 = bf2f(h16[(size_t)(unsigned)(p3 & 0xffffffffu) * DF + f]);
        acc0 += __uint_as_float((unsigned)(p0 >> 32)) * v0;
        acc1 += __uint_as_float((unsigned)(p1 >> 32)) * v1;
        acc2 += __uint_as_float((unsigned)(p2 >> 32)) * v2;
        acc3 += __uint_as_float((unsigned)(p3 >> 32)) * v3;
    }
    for (; i < s1; i++) {
        u64 p = packed[i];
        acc0 += __uint_as_float((unsigned)(p >> 32))
              * bf2f(h16[(size_t)(unsigned)(p & 0xffffffffu) * DF + f]);
    }
    float acc = (acc0 + acc1) + (acc2 + acc3);
    size_t o = (size_t)node * DF + f;
    if (MODE == 0)      { hn16[o] = f2bf(acc); out[o] = emb[o] + acc; }
    else if (MODE == 1) { hn16[o] = f2bf(acc); out[o] += acc; }
    else                { out[o] = (out[o] + acc) * 0.25f; }
}

// ======================= fallback (R1 atomic path, f32) =======================

__global__ void spmm_scatter(const int* __restrict__ src, const int* __restrict__ dst,
                             const float* __restrict__ w, const float* __restrict__ h,
                             float* __restrict__ hn, int nE) {
    int i = blockIdx.x * blockDim.x + threadIdx.x;
    int total = nE * 8;
    if (i >= total) return;
    int e = i >> 3, g = i & 7;
    int s = src[e], t = dst[e];
    float wt = w[e];
    float4 v = reinterpret_cast<const float4*>(h)[(size_t)s * 8 + g];
    float* p = hn + (size_t)t * DF + g * 4;
    atomicAdd(p + 0, v.x * wt); atomicAdd(p + 1, v.y * wt);
    atomicAdd(p + 2, v.z * wt); atomicAdd(p + 3, v.w * wt);
}
__global__ void accum_first(const float* __restrict__ emb, const float* __restrict__ hn,
                            float* __restrict__ out, int n4) {
    int i = blockIdx.x * blockDim.x + threadIdx.x;
    if (i >= n4) return;
    float4 a = reinterpret_cast<const float4*>(emb)[i];
    float4 b = reinterpret_cast<const float4*>(hn)[i];
    reinterpret_cast<float4*>(out)[i] = make_float4(a.x+b.x, a.y+b.y, a.z+b.z, a.w+b.w);
}
__global__ void accum_mid(const float* __restrict__ hn, float* __restrict__ out, int n4) {
    int i = blockIdx.x * blockDim.x + threadIdx.x;
    if (i >= n4) return;
    float4 a = reinterpret_cast<float4*>(out)[i];
    float4 b = reinterpret_cast<const float4*>(hn)[i];
    reinterpret_cast<float4*>(out)[i] = make_float4(a.x+b.x, a.y+b.y, a.z+b.z, a.w+b.w);
}
__global__ void accum_last(const float* __restrict__ hn, float* __restrict__ out, int n4) {
    int i = blockIdx.x * blockDim.x + threadIdx.x;
    if (i >= n4) return;
    float4 a = reinterpret_cast<float4*>(out)[i];
    float4 b = reinterpret_cast<const float4*>(hn)[i];
    reinterpret_cast<float4*>(out)[i] = make_float4((a.x+b.x)*0.25f, (a.y+b.y)*0.25f,
                                                    (a.z+b.z)*0.25f, (a.w+b.w)*0.25f);
}

// ======================= launch =======================

extern "C" void kernel_launch(void* const* d_in, const int* in_sizes, int n_in,
                              void* d_out, int out_size, void* d_ws, size_t ws_size,
                              hipStream_t stream) {
    const float* emb = (const float*)d_in[0];
    const int*   src = (const int*)d_in[1];
    const int*   dst = (const int*)d_in[2];
    const float* w   = (const float*)d_in[3];
    float* out = (float*)d_out;

    const int nN = in_sizes[0] / DF;
    const int nE = in_sizes[1];
    const int nbuck = (nN + BN - 1) / BN;
    const size_t hbytes  = (size_t)nN * DF * sizeof(float);   // f32 matrix
    const size_t h16b    = (size_t)nN * DF * 2;               // bf16 matrix

    char* ws = (char*)d_ws;
    // fast-path layout:
    //   [0, h16b)           E16  (bf16 emb)
    //   [h16b, 3*h16b)      B16, A16  -- also overlapped by rec_g (dead pre-pull)
    //   [off_pk, +nE*8)     packed
    //   rowptr, counters
    u16* E16 = (u16*)ws;
    u16* B16 = (u16*)(ws + h16b);
    u16* A16 = (u16*)(ws + 2 * h16b);
    u64* rec_g = (u64*)(ws + h16b);
    size_t recb = (((size_t)nE * 8 + 63) / 64) * 64;
    size_t off_pk = h16b + (recb > 2 * h16b ? recb : 2 * h16b);
    u64* packed = (u64*)(ws + off_pk);
    size_t roff = off_pk + recb;
    int* rowptr = (int*)(ws + roff);
    size_t boff = roff + (((size_t)(nN + 1) * 4 + 63) / 64) * 64;
    int* bcnt = (int*)(ws + boff);
    int* bptr = bcnt + MAXB;
    int* bcur = bptr + MAXB + 1;
    const size_t need = boff + (size_t)(3 * MAXB + 1) * 4;

    const dim3 blk(256);

    if (nbuck <= MAXB && nN < (1 << 24) && ws_size >= need) {
        const int n4 = nN * DF / 4;
        hipMemsetAsync(bcnt, 0, MAXB * 4, stream);
        k_cast<<<(n4 + 255) / 256, blk, 0, stream>>>(emb, E16, n4);
        k_bcount<<<512, blk, 0, stream>>>(dst, bcnt, nE, nbuck);
        k_bscan<<<1, MAXB, 0, stream>>>(bcnt, bptr, bcur, nbuck);
        k_bpart<<<(nE + CHUNK - 1) / CHUNK, 512, 0, stream>>>(src, dst, w, bcur,
                                                              rec_g, nE, nbuck);
        k_csr<<<nbuck, 512, 0, stream>>>(bptr, rec_g, rowptr, packed, nN, nbuck);

        const int pgrid = (nN * 32 + 255) / 256;
        k_pull<0><<<pgrid, blk, 0, stream>>>(rowptr, packed, E16, B16, emb, out, nN);
        k_pull<1><<<pgrid, blk, 0, stream>>>(rowptr, packed, B16, A16, emb, out, nN);
        k_pull<2><<<pgrid, blk, 0, stream>>>(rowptr, packed, A16, B16, emb, out, nN);
    } else {
        float* A = (float*)ws;
        float* B = (float*)(ws + hbytes);
        const int n4 = nN * DF / 4;
        const int sgrid = (nE * 8 + 255) / 256;
        const int agrid = (n4 + 255) / 256;
        hipMemsetAsync(B, 0, hbytes, stream);
        spmm_scatter<<<sgrid, blk, 0, stream>>>(src, dst, w, emb, B, nE);
        accum_first<<<agrid, blk, 0, stream>>>(emb, B, out, n4);
        hipMemsetAsync(A, 0, hbytes, stream);
        spmm_scatter<<<sgrid, blk, 0, stream>>>(src, dst, w, B, A, nE);
        accum_mid<<<agrid, blk, 0, stream>>>(A, out, n4);
        hipMemsetAsync(B, 0, hbytes, stream);
        spmm_scatter<<<sgrid, blk, 0, stream>>>(src, dst, w, A, B, nE);
        accum_last<<<agrid, blk, 0, stream>>>(B, out, n4);
    }
}